// Round 14
// baseline (420.462 us; speedup 1.0000x reference)
//
#include <hip/hip_runtime.h>

typedef __attribute__((ext_vector_type(4))) float f32x4;
typedef __attribute__((ext_vector_type(16))) float f32x16;
typedef __attribute__((ext_vector_type(8))) short short8;
typedef __attribute__((ext_vector_type(4))) short short4v;

#define PADW(I) ((I) + ((I) >> 4))
#define WOFF(z) ((z) + ((z) >> 4))

constexpr int LROW = 4096;
constexpr int KW   = 64;
constexpr int HALO = 32;
constexpr int NLOG = LROW + 2 * HALO;         // 4160 entries
constexpr int XS_SIZE = PADW(NLOG - 1) + 1;   // 4419 f32 words (17676 B)

// Level-array layout: entry n at byte L(n) = 2n + 16*(n>>5)
// (16B pad per 32-entry block => 80B block stride; pads never accessed).
constexpr int AS    = 10384;       // 130 blocks * 80B - 16 pad of last + ... = L(4159)+2 rounded to 16
constexpr int SLOT  = 3 * AS;      // h, m*2^8, l*2^16 arrays     (31152 B)
constexpr int POOLB = 2 * SLOT;    // double buffer               (62304 B)
static_assert(XS_SIZE * 4 <= SLOT, "f32 y stage fits in buf1 region");
static_assert(POOLB + 2 * KW * 4 <= 65536, "static LDS limit");

__device__ __forceinline__ float bfh2f(unsigned short h) {
  return __uint_as_float(((unsigned)h) << 16);
}
__device__ __forceinline__ unsigned short btrunc(float x) {
  return (unsigned short)(__float_as_uint(x) >> 16);
}
// exact scaled split: x = h + m*2^-8 + l*2^-16 + O(2^-24 x); all steps exact.
__device__ __forceinline__ void split3s(float x, unsigned short& h,
                                        unsigned short& m, unsigned short& l) {
  h = btrunc(x);
  float r1 = (x - bfh2f(h)) * 256.0f;
  m = btrunc(r1);
  float r2 = (r1 - bfh2f(m)) * 256.0f;
  l = btrunc(r2);
}
__device__ __forceinline__ float shrinkf(float c, float theta) {
  float a = fabsf(c) - theta;
  return (a > 0.0f) ? copysignf(a, c) : 0.0f;
}

// scalar conv (R6-proven): thread owns outputs [16t,16t+16), affine LDS base.
__device__ __forceinline__ void conv_row(const float* __restrict__ xw,
                                         const float* __restrict__ kn,
                                         float acc[16]) {
#pragma unroll
  for (int e = 0; e < 16; ++e) acc[e] = 0.0f;
#pragma unroll
  for (int m = 0; m < 79; ++m) {
    float wv = xw[WOFF(1 + m)];
    const int jlo = (m - 15 > 0) ? (m - 15) : 0;
    const int jhi = (m < 63) ? m : 63;
#pragma unroll
    for (int j = jlo; j <= jhi; ++j) acc[m - j] = fmaf(kn[j], wv, acc[m - j]);
  }
}

// One block = one row. 4 waves; wave w owns x-indices [1024w, 1024w+1024) as
// ONE 32x32 D tile: out[1024w + 32*pcol + e], pcol = lane&31 (D col),
// e = (reg&3)+8*(reg>>2)+4*(lane>>5) (D row, m74-verified mapping).
// GEMM: D[e][p] = sum_q Kmat[e][q] * x[1024w+32p-32+q], q in [0,96) = 6 kf of 16.
// Kmat = I - K/L (band d = q-e-1 in [0,64); identity at q = e+32).
// Entry n = x_index + 32; B[q][p] is entry 32*(32w+p) + q.
__global__ __launch_bounds__(256, 2) void ista_mfma(
    const float* __restrict__ y, const float* __restrict__ pulse,
    float* __restrict__ xout) {
  __shared__ __align__(16) char pool[POOLB];
  __shared__ float pl[KW];
  __shared__ float knl[KW];

  const int t = threadIdx.x, w = t >> 6, l = t & 63;
  const int lq = l & 31;              // D col (pcol) / A row (e-residue)
  const int hi = l >> 5;              // k-subgroup
  const int row = blockIdx.x;

  if (t < KW) pl[t] = pulse[t];

  // zero buf0 halos of 3 level arrays: entries [0,32)->bytes[0,64),
  // entries [4128,4160)->bytes[10320,10384)
#pragma unroll
  for (int a = 0; a < 3; ++a) {
    char* ab = pool + a * AS;
    if (t < 16) *(unsigned*)(ab + 4 * t) = 0u;
    if (t < 16) *(unsigned*)(ab + 10320 + 4 * t) = 0u;
  }

  // stage y as f32 (PADW layout) into the buf1 region (for exact scalar bt)
  float* yw = (float*)(pool + SLOT);
  if (t < HALO) { yw[PADW(t)] = 0.0f; yw[PADW(NLOG - HALO + t)] = 0.0f; }
  const float* yrow = y + (size_t)row * LROW;
#pragma unroll
  for (int q = 0; q < 4; ++q) {
    int i4 = q * 256 + t; float4 v = ((const float4*)yrow)[i4];
    yw[PADW(HALO + 4 * i4 + 0)] = v.x; yw[PADW(HALO + 4 * i4 + 1)] = v.y;
    yw[PADW(HALO + 4 * i4 + 2)] = v.z; yw[PADW(HALO + 4 * i4 + 3)] = v.w;
  }
  __syncthreads();                       // (A) pl, y staged

  float Lc = 0.0f;
#pragma unroll
  for (int j = 0; j < KW; ++j) Lc += pl[j] * pl[j];
  const float theta = 0.1f / Lc, invL = 1.0f / Lc;
  if (t < KW) knl[t] = pl[KW - 1 - t] * invL;

  // operator A-frags for I - K/L, exact scaled bf16x3.
  // A[e=lq][q = 16kf + 8hi + j]
  short8 Ah[6], Am[6], Al[6];
#pragma unroll
  for (int kf = 0; kf < 6; ++kf) {
#pragma unroll
    for (int j = 0; j < 8; ++j) {
      int q = 16 * kf + 8 * hi + j, d = q - lq - 1;
      float v = (d >= 0 && d < 64) ? pl[63 - d] * invL : 0.0f;
      float vc = ((q == lq + 32) ? 1.0f : 0.0f) - v;
      unsigned short h, m, lo; split3s(vc, h, m, lo);
      Ah[kf][j] = (short)h; Am[kf][j] = (short)m; Al[kf][j] = (short)lo;
    }
  }
  __syncthreads();                       // (B) knl visible

  // exact f32 B_term via scalar conv (one-time), thread-t element layout
  float bts[16];
  conv_row(yw + 17 * t, knl, bts);
  __syncthreads();                       // (C) all y reads done

  // re-layout bt through (dead) y region, read back in 32x32 C-layout
#pragma unroll
  for (int e = 0; e < 16; ++e) (yw + 17 * t)[WOFF(32 + e)] = bts[e];
  __syncthreads();                       // (D)

  f32x16 bt;
#pragma unroll
  for (int r = 0; r < 16; ++r) {
    const int e = (r & 3) + 8 * (r >> 2) + 4 * hi;
    bt[r] = yw[PADW(32 + 1024 * w + 32 * lq + e)];
  }
  __syncthreads();                       // (E) bt reads done; buf1 free

  // zero buf1 halos
#pragma unroll
  for (int a = 0; a < 3; ++a) {
    char* ab = pool + SLOT + a * AS;
    if (t < 16) *(unsigned*)(ab + 4 * t) = 0u;
    if (t < 16) *(unsigned*)(ab + 10320 + 4 * t) = 0u;
  }

  // lane-constant byte bases
  const int rbL = 80 * (32 * w + lq) + 16 * hi;       // B-frag reads (b128)
  const int wbL = 80 * (32 * w + lq + 1) + 8 * hi;    // C writes (b64 groups)
  constexpr float S8 = 1.0f / 256.0f, S16 = 1.0f / 65536.0f;

  // x1 = shrink(bt) -> buf1 (C-write path)
  {
    unsigned short hh[16], mm[16], ll[16];
#pragma unroll
    for (int i = 0; i < 16; ++i) {
      float xn = shrinkf(bt[i], theta);
      split3s(xn, hh[i], mm[i], ll[i]);
    }
    char* wpb = pool + SLOT;
#pragma unroll
    for (int g = 0; g < 4; ++g) {
      short4v h4, m4, l4;
#pragma unroll
      for (int i = 0; i < 4; ++i) {
        h4[i] = (short)hh[4 * g + i]; m4[i] = (short)mm[4 * g + i];
        l4[i] = (short)ll[4 * g + i];
      }
      char* wp = wpb + wbL + 16 * g;
      *(short4v*)(wp)          = h4;
      *(short4v*)(wp + AS)     = m4;
      *(short4v*)(wp + 2 * AS) = l4;
    }
  }
  __syncthreads();                       // (F) x1 visible

  // 19 iterations; scale-grouped accumulators; double-buffer, 1 barrier/iter
  for (int it = 0; it < 19; ++it) {
    const int rs = (it & 1) ? 0 : SLOT, ws = SLOT - rs;
    const char* rp = pool + rs + rbL;
    f32x16 ah = bt, am = (f32x16)0.0f, al = (f32x16)0.0f;
#pragma unroll
    for (int kf = 0; kf < 6; ++kf) {
      const char* p = rp + (32 * kf + 16 * (kf >> 1));   // L() block carry
      short8 xh = *(const short8*)(p);
      short8 xm = *(const short8*)(p + AS);
      short8 xl = *(const short8*)(p + 2 * AS);
      ah = __builtin_amdgcn_mfma_f32_32x32x16_bf16(Ah[kf], xh, ah, 0, 0, 0);
      am = __builtin_amdgcn_mfma_f32_32x32x16_bf16(Ah[kf], xm, am, 0, 0, 0);
      am = __builtin_amdgcn_mfma_f32_32x32x16_bf16(Am[kf], xh, am, 0, 0, 0);
      al = __builtin_amdgcn_mfma_f32_32x32x16_bf16(Ah[kf], xl, al, 0, 0, 0);
      al = __builtin_amdgcn_mfma_f32_32x32x16_bf16(Am[kf], xm, al, 0, 0, 0);
      al = __builtin_amdgcn_mfma_f32_32x32x16_bf16(Al[kf], xh, al, 0, 0, 0);
    }
    unsigned short hh[16], mm[16], ll[16];
#pragma unroll
    for (int i = 0; i < 16; ++i) {
      float c  = fmaf(S16, al[i], fmaf(S8, am[i], ah[i]));
      float xn = shrinkf(c, theta);
      split3s(xn, hh[i], mm[i], ll[i]);
    }
    char* wpb = pool + ws;
#pragma unroll
    for (int g = 0; g < 4; ++g) {
      short4v h4, m4, l4;
#pragma unroll
      for (int i = 0; i < 4; ++i) {
        h4[i] = (short)hh[4 * g + i]; m4[i] = (short)mm[4 * g + i];
        l4[i] = (short)ll[4 * g + i];
      }
      char* wp = wpb + wbL + 16 * g;
      *(short4v*)(wp)          = h4;
      *(short4v*)(wp + AS)     = m4;
      *(short4v*)(wp + 2 * AS) = l4;
    }
    __syncthreads();
  }

  // final x in buf0: thread t reads entries [16t+32, 16t+48), reconstructs,
  // writes coalesced float4. Base byte = L(16t+32) = 32t + 64 + 16*((t+2)>>1).
  {
    const int base = 32 * t + 64 + 16 * ((t + 2) >> 1);
    float o[16];
#pragma unroll
    for (int s = 0; s < 2; ++s) {
      const char* hp = pool + base + 16 * s;
      short8 hv = *(const short8*)(hp);
      short8 mv = *(const short8*)(hp + AS);
      short8 lv = *(const short8*)(hp + 2 * AS);
#pragma unroll
      for (int c2 = 0; c2 < 8; ++c2) {
        float xv = fmaf(S8, bfh2f((unsigned short)mv[c2]),
                        bfh2f((unsigned short)hv[c2]));
        o[8 * s + c2] = fmaf(S16, bfh2f((unsigned short)lv[c2]), xv);
      }
    }
    float4* xr = (float4*)(xout + (size_t)row * LROW + 16 * t);
#pragma unroll
    for (int s = 0; s < 4; ++s)
      xr[s] = make_float4(o[4 * s], o[4 * s + 1], o[4 * s + 2], o[4 * s + 3]);
  }
}

// ---------------- MLP via bf16 MFMA (validated in R2) ----------------
__device__ __forceinline__ unsigned short f2bf(float f) {
  unsigned u = __float_as_uint(f);
  u += 0x7fffu + ((u >> 16) & 1u);      // RNE
  return (unsigned short)(u >> 16);
}

__global__ __launch_bounds__(256) void cast_w1(const float* __restrict__ W1,
                                               unsigned short* __restrict__ W1p) {
  const int kq = blockIdx.x;
  const int c  = threadIdx.x;
  short8 v;
#pragma unroll
  for (int j = 0; j < 8; ++j)
    v[j] = (short)f2bf(W1[(size_t)(kq * 8 + j) * 256 + c]);
  *(short8*)(W1p + ((size_t)kq * 256 + c) * 8) = v;
}

__global__ __launch_bounds__(256) void mlp_mfma(
    const float* __restrict__ x, const unsigned short* __restrict__ W1p,
    const float* __restrict__ b1, const float* __restrict__ W2,
    const float* __restrict__ b2, float* __restrict__ out1) {
  __shared__ short Ap[16 * 8 * 8];
  __shared__ short Bp[8 * 256 * 8];
  __shared__ float pr[4][16];

  const int t = threadIdx.x;
  const int w = t >> 6;
  const int l = t & 63;
  const int lrow = l & 15;
  const int lk   = l >> 4;
  const int row0 = blockIdx.x * 16;

  f32x4 acc[4];
#pragma unroll
  for (int n = 0; n < 4; ++n) acc[n] = (f32x4)0.0f;

  for (int kt = 0; kt < 64; ++kt) {
    __syncthreads();
    {
      const int r  = t >> 4;
      const int k4 = t & 15;
      const float4 v = *(const float4*)(x + (size_t)(row0 + r) * LROW + kt * 64 + k4 * 4);
      short4v a;
      a.x = (short)f2bf(v.x); a.y = (short)f2bf(v.y);
      a.z = (short)f2bf(v.z); a.w = (short)f2bf(v.w);
      const int kq = k4 >> 1, h = k4 & 1;
      *(short4v*)((char*)Ap + ((r * 8 + (kq ^ (r & 7))) * 16 + h * 8)) = a;
    }
    {
      const short8* src = (const short8*)(W1p + (size_t)kt * (8 * 256 * 8));
      short8* dst = (short8*)Bp;
#pragma unroll
      for (int i = 0; i < 8; ++i) dst[t + 256 * i] = src[t + 256 * i];
    }
    __syncthreads();
#pragma unroll
    for (int kf = 0; kf < 2; ++kf) {
      const int kq = kf * 4 + lk;
      short8 af = *(short8*)((char*)Ap + (lrow * 8 + (kq ^ (lrow & 7))) * 16);
#pragma unroll
      for (int n = 0; n < 4; ++n) {
        short8 bf = *(short8*)((char*)Bp + (kq * 256 + w * 64 + n * 16 + lrow) * 16);
        acc[n] = __builtin_amdgcn_mfma_f32_16x16x32_bf16(af, bf, acc[n], 0, 0, 0);
      }
    }
  }

  float s[4] = {0.0f, 0.0f, 0.0f, 0.0f};
#pragma unroll
  for (int n = 0; n < 4; ++n) {
    const int c = w * 64 + n * 16 + lrow;
    const float b1v = b1[c];
    const float w2v = W2[c];
#pragma unroll
    for (int i = 0; i < 4; ++i) {
      float f = acc[n][i] + b1v;
      f = fmaxf(f, 0.0f);
      s[i] = fmaf(f, w2v, s[i]);
    }
  }
#pragma unroll
  for (int off = 1; off < 16; off <<= 1) {
#pragma unroll
    for (int i = 0; i < 4; ++i) s[i] += __shfl_xor(s[i], off, 64);
  }
  if (lrow == 0) {
#pragma unroll
    for (int i = 0; i < 4; ++i) pr[w][lk * 4 + i] = s[i];
  }
  __syncthreads();
  if (t < 16) {
    out1[row0 + t] =
        (pr[0][t] + pr[1][t] + pr[2][t] + pr[3][t] + b2[0]) * (float)LROW;
  }
}

extern "C" void kernel_launch(void* const* d_in, const int* in_sizes, int n_in,
                              void* d_out, int out_size, void* d_ws, size_t ws_size,
                              hipStream_t stream) {
  const float* y     = (const float*)d_in[0];
  const float* pulse = (const float*)d_in[1];
  const float* W1    = (const float*)d_in[2];
  const float* b1    = (const float*)d_in[3];
  const float* W2    = (const float*)d_in[4];
  const float* b2    = (const float*)d_in[5];

  float* xout = (float*)d_out;
  float* out1 = xout + (size_t)LROW * LROW;
  unsigned short* W1p = (unsigned short*)d_ws;

  cast_w1<<<512, 256, 0, stream>>>(W1, W1p);
  ista_mfma<<<LROW, 256, 0, stream>>>(y, pulse, xout);
  mlp_mfma<<<LROW / 16, 256, 0, stream>>>(xout, W1p, b1, W2, b2, out1);
}